// Round 7
// baseline (19.902 us; speedup 1.0000x reference)
//
#include <hip/hip_runtime.h>

// out[i,j,k] = sum_h X[i+1,h]*X[j+1,h]*Wp[h,k] + b[k]
// (symmetrization cancels the antisymmetric d-terms; prod_term symmetric)
//
// R7: same fused MFMA computation as R6 (validated), regridded for makespan:
// 144 blocks x 512 thr (8 waves). Each block owns 4 tiles; each tile is
// computed by 2 waves with split-K x2 + LDS reduce. 144 < 256 CUs => every
// CU runs exactly one block: makespan = ONE block latency (R6 had 2.25
// blocks/CU -> 3 serial block latencies on the critical CU), and 2 waves/SIMD
// instead of 1.1 for latency hiding.

typedef __attribute__((ext_vector_type(8))) short frag_ab;  // 8 bf16
typedef __attribute__((ext_vector_type(4))) float f32x4;

constexpr int Hd  = 768;
constexpr int OUT = 382;
constexpr int NTI = 24;     // 16-tiles per dim (24*16 = 384)

static __device__ __forceinline__ unsigned short bfc(float f) {
  return __builtin_bit_cast(unsigned short, (__bf16)f);   // RNE f32->bf16
}
static __device__ __forceinline__ frag_ab pack8(const float4& a, const float4& b) {
  frag_ab r;
  r[0] = (short)bfc(a.x); r[1] = (short)bfc(a.y);
  r[2] = (short)bfc(a.z); r[3] = (short)bfc(a.w);
  r[4] = (short)bfc(b.x); r[5] = (short)bfc(b.y);
  r[6] = (short)bfc(b.z); r[7] = (short)bfc(b.w);
  return r;
}

__global__ __launch_bounds__(512)
void fused_kernel(const float* __restrict__ X, const float* __restrict__ W,
                  const float* __restrict__ bias, float* __restrict__ out) {
  __shared__ float red[4][512];           // per-tile cross-wave reduce slots

  const int w    = threadIdx.x >> 6;      // wave 0..7
  const int tl   = w >> 1;                // tile slot in block 0..3
  const int half = w & 1;                 // K-split half
  const int tile = blockIdx.x * 4 + tl;   // 0..575
  const int mi = tile / NTI;
  const int nj = tile % NTI;
  const int l  = threadIdx.x & 63;
  const int lr = l & 15;                  // fragment row
  const int lg = l >> 4;                  // k-group 0..3

  const int gi = mi * 16 + lr;            // A row this lane loads
  const int gj = nj * 16 + lr;            // B row this lane loads
  const float* Xi = X + (size_t)(gi + 1) * Hd;
  const float* Xj = X + (size_t)(gj + 1) * Hd;
  const bool vi = (gi < 383);             // X row gi+1 in bounds
  const bool vj = (gj < 383);

  f32x4 acc0 = {}, acc1 = {};
  #pragma unroll
  for (int s = 0; s < 12; ++s) {          // this wave's 12 of 24 k-slices
    const int h = (half * 12 + s) * 32 + lg * 8;
    float4 xa0 = {}, xa1 = {}, xb0 = {}, xb1 = {};
    if (vi) { xa0 = *reinterpret_cast<const float4*>(Xi + h);
              xa1 = *reinterpret_cast<const float4*>(Xi + h + 4); }
    if (vj) { xb0 = *reinterpret_cast<const float4*>(Xj + h);
              xb1 = *reinterpret_cast<const float4*>(Xj + h + 4); }
    // W rows h..h+7, interleaved (h,k): even floats k=0, odd floats k=1
    const float4 w0 = *reinterpret_cast<const float4*>(W + 2 * h);
    const float4 w1 = *reinterpret_cast<const float4*>(W + 2 * h + 4);
    const float4 w2 = *reinterpret_cast<const float4*>(W + 2 * h + 8);
    const float4 w3 = *reinterpret_cast<const float4*>(W + 2 * h + 12);

    const frag_ab a = pack8(xa0, xa1);
    const float4 b0lo = make_float4(xb0.x * w0.x, xb0.y * w0.z, xb0.z * w1.x, xb0.w * w1.z);
    const float4 b0hi = make_float4(xb1.x * w2.x, xb1.y * w2.z, xb1.z * w3.x, xb1.w * w3.z);
    const float4 b1lo = make_float4(xb0.x * w0.y, xb0.y * w0.w, xb0.z * w1.y, xb0.w * w1.w);
    const float4 b1hi = make_float4(xb1.x * w2.y, xb1.y * w2.w, xb1.z * w3.y, xb1.w * w3.w);
    const frag_ab b0 = pack8(b0lo, b0hi);
    const frag_ab b1 = pack8(b1lo, b1hi);

    acc0 = __builtin_amdgcn_mfma_f32_16x16x32_bf16(a, b0, acc0, 0, 0, 0);
    acc1 = __builtin_amdgcn_mfma_f32_16x16x32_bf16(a, b1, acc1, 0, 0, 0);
  }

  // cross-wave K-reduce: odd wave parks partials, even wave combines + stores
  if (half == 1) {
    #pragma unroll
    for (int r = 0; r < 4; ++r) {
      red[tl][r * 64 + l]       = acc0[r];  // consecutive lanes -> banks
      red[tl][256 + r * 64 + l] = acc1[r];
    }
  }
  __syncthreads();
  if (half == 0) {
    #pragma unroll
    for (int r = 0; r < 4; ++r) {
      acc0[r] += red[tl][r * 64 + l];
      acc1[r] += red[tl][256 + r * 64 + l];
    }
    const float b0v = bias[0], b1v = bias[1];
    #pragma unroll
    for (int r = 0; r < 4; ++r) {  // C/D: col = lane&15, row = (lane>>4)*4 + r
      const int i = mi * 16 + lg * 4 + r;
      const int j = nj * 16 + lr;
      if (i < OUT && j < OUT)
        *reinterpret_cast<float2*>(&out[((size_t)i * OUT + j) * 2]) =
            make_float2(acc0[r] + b0v, acc1[r] + b1v);
    }
  }
}

extern "C" void kernel_launch(void* const* d_in, const int* in_sizes, int n_in,
                              void* d_out, int out_size, void* d_ws, size_t ws_size,
                              hipStream_t stream) {
  const float* X    = (const float*)d_in[0];  // (1,384,768) fp32
  // d_in[1] = sequence_lengths (dead: output independent of it)
  const float* W    = (const float*)d_in[2];  // (1536,2) fp32; rows [0,768) = Wp
  const float* bias = (const float*)d_in[3];  // (2,)
  float* out = (float*)d_out;                 // (1,382,382,2) fp32

  fused_kernel<<<dim3(144, 1, 1), dim3(512, 1, 1), 0, stream>>>(X, W, bias, out);
}

// Round 8
// 13.612 us; speedup vs baseline: 1.4621x; 1.4621x over previous
//
#include <hip/hip_runtime.h>

// out[i,j,k] = sum_h X[i+1,h]*X[j+1,h]*Wp[h,k] + b[k]
// (symmetrization cancels the antisymmetric d-terms; prod_term symmetric)
//
// R8: R6's validated structure (single dispatch, 128-thr blocks, one 16x16
// tile per 2 waves, split-K x2, LDS reduce) + triangular grid: only tiles
// with nj >= mi are computed (300 blocks), off-diagonal tiles mirror-store
// to both (i,j) and (j,i). Halves loads/VALU/MFMA at identical structure --
// discriminates work-bound vs floor-bound.

typedef __attribute__((ext_vector_type(8))) short frag_ab;  // 8 bf16
typedef __attribute__((ext_vector_type(4))) float f32x4;

constexpr int Hd  = 768;
constexpr int OUT = 382;
constexpr int NTI = 24;                       // 16-tiles per dim
constexpr int NBLK = NTI * (NTI + 1) / 2;     // 300 upper-tri tiles

static __device__ __forceinline__ unsigned short bfc(float f) {
  return __builtin_bit_cast(unsigned short, (__bf16)f);   // RNE f32->bf16
}
static __device__ __forceinline__ frag_ab pack8(const float4& a, const float4& b) {
  frag_ab r;
  r[0] = (short)bfc(a.x); r[1] = (short)bfc(a.y);
  r[2] = (short)bfc(a.z); r[3] = (short)bfc(a.w);
  r[4] = (short)bfc(b.x); r[5] = (short)bfc(b.y);
  r[6] = (short)bfc(b.z); r[7] = (short)bfc(b.w);
  return r;
}

__global__ __launch_bounds__(128)
void fused_kernel(const float* __restrict__ X, const float* __restrict__ W,
                  const float* __restrict__ bias, float* __restrict__ out) {
  __shared__ float red[512];              // cross-wave reduce

  // triangular block index -> (mi, nj), nj >= mi  (validated in R3)
  const int m = blockIdx.x;
  int mi = (int)(((2 * NTI + 1) - sqrtf((float)((2 * NTI + 1) * (2 * NTI + 1) - 8 * m))) * 0.5f);
  while (mi > 0 && (mi * NTI - mi * (mi - 1) / 2) > m) --mi;
  while (((mi + 1) * NTI - (mi + 1) * mi / 2) <= m) ++mi;
  const int nj = mi + (m - (mi * NTI - mi * (mi - 1) / 2));

  const int half = threadIdx.x >> 6;      // K-split half (0 or 1)
  const int l  = threadIdx.x & 63;
  const int lr = l & 15;                  // fragment row
  const int lg = l >> 4;                  // k-group 0..3

  const int gi = mi * 16 + lr;            // A row this lane loads
  const int gj = nj * 16 + lr;            // B row this lane loads
  const float* Xi = X + (size_t)(gi + 1) * Hd;
  const float* Xj = X + (size_t)(gj + 1) * Hd;
  const bool vi = (gi < 383);             // X row gi+1 in bounds
  const bool vj = (gj < 383);

  f32x4 acc0 = {}, acc1 = {};
  #pragma unroll
  for (int s = 0; s < 12; ++s) {          // this wave's 12 of 24 k-slices
    const int h = (half * 12 + s) * 32 + lg * 8;
    float4 xa0 = {}, xa1 = {}, xb0 = {}, xb1 = {};
    if (vi) { xa0 = *reinterpret_cast<const float4*>(Xi + h);
              xa1 = *reinterpret_cast<const float4*>(Xi + h + 4); }
    if (vj) { xb0 = *reinterpret_cast<const float4*>(Xj + h);
              xb1 = *reinterpret_cast<const float4*>(Xj + h + 4); }
    // W rows h..h+7, interleaved (h,k): even floats k=0, odd floats k=1
    const float4 w0 = *reinterpret_cast<const float4*>(W + 2 * h);
    const float4 w1 = *reinterpret_cast<const float4*>(W + 2 * h + 4);
    const float4 w2 = *reinterpret_cast<const float4*>(W + 2 * h + 8);
    const float4 w3 = *reinterpret_cast<const float4*>(W + 2 * h + 12);

    const frag_ab a = pack8(xa0, xa1);
    const float4 b0lo = make_float4(xb0.x * w0.x, xb0.y * w0.z, xb0.z * w1.x, xb0.w * w1.z);
    const float4 b0hi = make_float4(xb1.x * w2.x, xb1.y * w2.z, xb1.z * w3.x, xb1.w * w3.z);
    const float4 b1lo = make_float4(xb0.x * w0.y, xb0.y * w0.w, xb0.z * w1.y, xb0.w * w1.w);
    const float4 b1hi = make_float4(xb1.x * w2.y, xb1.y * w2.w, xb1.z * w3.y, xb1.w * w3.w);
    const frag_ab b0 = pack8(b0lo, b0hi);
    const frag_ab b1 = pack8(b1lo, b1hi);

    acc0 = __builtin_amdgcn_mfma_f32_16x16x32_bf16(a, b0, acc0, 0, 0, 0);
    acc1 = __builtin_amdgcn_mfma_f32_16x16x32_bf16(a, b1, acc1, 0, 0, 0);
  }

  // cross-wave K-reduce: wave 1 parks partials, wave 0 combines + stores
  if (half == 1) {
    #pragma unroll
    for (int r = 0; r < 4; ++r) {
      red[r * 64 + l]       = acc0[r];
      red[256 + r * 64 + l] = acc1[r];
    }
  }
  __syncthreads();
  if (half == 0) {
    #pragma unroll
    for (int r = 0; r < 4; ++r) {
      acc0[r] += red[r * 64 + l];
      acc1[r] += red[256 + r * 64 + l];
    }
    const float b0v = bias[0], b1v = bias[1];
    #pragma unroll
    for (int r = 0; r < 4; ++r) {  // C/D: col = lane&15, row = (lane>>4)*4 + r
      const int i = mi * 16 + lg * 4 + r;
      const int j = nj * 16 + lr;
      if (i < OUT && j < OUT) {
        const float2 v = make_float2(acc0[r] + b0v, acc1[r] + b1v);
        *reinterpret_cast<float2*>(&out[((size_t)i * OUT + j) * 2]) = v;
        if (mi != nj)   // mirror tile (diagonal tiles cover both orders)
          *reinterpret_cast<float2*>(&out[((size_t)j * OUT + i) * 2]) = v;
      }
    }
  }
}

extern "C" void kernel_launch(void* const* d_in, const int* in_sizes, int n_in,
                              void* d_out, int out_size, void* d_ws, size_t ws_size,
                              hipStream_t stream) {
  const float* X    = (const float*)d_in[0];  // (1,384,768) fp32
  // d_in[1] = sequence_lengths (dead: output independent of it)
  const float* W    = (const float*)d_in[2];  // (1536,2) fp32; rows [0,768) = Wp
  const float* bias = (const float*)d_in[3];  // (2,)
  float* out = (float*)d_out;                 // (1,382,382,2) fp32

  fused_kernel<<<dim3(NBLK, 1, 1), dim3(128, 1, 1), 0, stream>>>(X, W, bias, out);
}